// Round 7
// baseline (234.562 us; speedup 1.0000x reference)
//
#include <hip/hip_runtime.h>

typedef unsigned short u16;
typedef unsigned int   u32;
typedef __bf16 bf16x8 __attribute__((ext_vector_type(8)));
typedef __bf16 bf16x4 __attribute__((ext_vector_type(4)));
typedef float  f32x4  __attribute__((ext_vector_type(4)));
typedef u32    u32x4  __attribute__((ext_vector_type(4)));
typedef u32    u32x2  __attribute__((ext_vector_type(2)));
typedef u16    u16x8  __attribute__((ext_vector_type(8)));

#define MFMA16(a,b,c) __builtin_amdgcn_mfma_f32_16x16x32_bf16(a,b,c,0,0,0)

#define BB 4
#define SS 2048
#define DD 1024
#define HH 16
#define DH 64
#define MM 8192   // B*S

#define QSCALE 0.0901684400555602f   // (1/16) * log2(e), folded into Q

// s_waitcnt vmcnt(0) ONLY (expcnt=7, lgkmcnt=0xF masked off): gfx9 encoding
#define WAIT_VM0() __builtin_amdgcn_s_waitcnt(0x0F70)

__device__ __forceinline__ u16 f2bf(float f) {
  u32 u = __builtin_bit_cast(u32, f);
  u += 0x7fffu + ((u >> 16) & 1u);   // RNE
  return (u16)(u >> 16);
}

// async global->LDS DMA, 16B per lane. LDS dest = wave-uniform base + lane*16.
__device__ __forceinline__ void async16(const void* g, void* l) {
  __builtin_amdgcn_global_load_lds(
      (const __attribute__((address_space(1))) unsigned int*)g,
      (__attribute__((address_space(3))) unsigned int*)l, 16, 0, 0);
}

// ---------------------------------------------------------------------------
// Kernel 0: x fp32 -> bf16 (hw packed cvt)
// ---------------------------------------------------------------------------
__global__ __launch_bounds__(256) void convert_x(
    const float* __restrict__ in, u16* __restrict__ out)
{
  const size_t stride = (size_t)gridDim.x * 256 * 8;
  for (size_t i = ((size_t)blockIdx.x * 256 + threadIdx.x) * 8;
       i < (size_t)MM * DD; i += stride) {
    f32x4 a = *(const f32x4*)(in + i);
    f32x4 b = *(const f32x4*)(in + i + 4);
    u32x2 ua = __builtin_bit_cast(u32x2, __builtin_convertvector(a, bf16x4));
    u32x2 ub = __builtin_bit_cast(u32x2, __builtin_convertvector(b, bf16x4));
    u32x4 v = {ua[0], ua[1], ub[0], ub[1]};
    *(u32x4*)(out + i) = v;
  }
}

__global__ __launch_bounds__(256) void fill_sig(float* __restrict__ out, int n)
{
  for (int i = blockIdx.x * 256 + threadIdx.x; i < n; i += gridDim.x * 256)
    out[i] = 3.0f;
}

// ---------------------------------------------------------------------------
// Kernel 1: W fp32 [K][N] -> Wt bf16 [N][K]
// ---------------------------------------------------------------------------
__global__ __launch_bounds__(256) void convert_w(
    const float* __restrict__ w0, const float* __restrict__ w1,
    const float* __restrict__ w2, u16* __restrict__ WtAll)
{
  const int z = blockIdx.z;
  const float* W = (z == 0) ? w0 : ((z == 1) ? w1 : w2);
  u16* Wt = WtAll + (size_t)z * DD * DD;
  const int n0 = blockIdx.x * 64;
  const int k0 = blockIdx.y * 64;
  __shared__ u16 tile[64][65];
#pragma unroll
  for (int i = 0; i < 16; ++i) {
    int e = threadIdx.x + i * 256;
    int r = e >> 6, c = e & 63;
    tile[r][c] = f2bf(W[(size_t)(k0 + r) * DD + n0 + c]);
  }
  __syncthreads();
#pragma unroll
  for (int i = 0; i < 16; ++i) {
    int e = threadIdx.x + i * 256;
    int r = e >> 6, c = e & 63;
    Wt[(size_t)(n0 + r) * DD + k0 + c] = tile[c][r];
  }
}

// ---------------------------------------------------------------------------
// Kernel 2: QKV GEMM — 256x128 tile, BK=64, 512 threads (8 waves, 4M x 2N).
// Round-17: same tile/counted-vmcnt plan as round-16, but using the
// TRIPLE-BUFFER + SINGLE raw-s_barrier control flow that is PROVEN to
// execute on this HW (round-15 attn ran it correctly). Per iter:
//   vmcnt(6)  — own 6 loads of tile kt are oldest of 12 outstanding
//   s_barrier — all waves' tile-kt slices complete
//   stage(kt+2, (kt+2)%3)  — WAR safe: that buffer last read at iter kt-1
//   compute buf[kt%3]
// Loads get ~2 compute phases of cover; never drained to 0 in the loop (T4).
// LDS = 3 x (A 256x64 + B 128x64) bf16 = 144 KB. Chunk-XOR swizzle carried.
// ---------------------------------------------------------------------------
__global__ __launch_bounds__(512, 1) void qkv_gemm(
    const u16* __restrict__ X, const u16* __restrict__ WtAll,
    u16* __restrict__ QKV)
{
  const int z = blockIdx.z;
  const u16* Wt = WtAll + (size_t)z * DD * DD;
  u16* Y = QKV + (size_t)z * MM * DD;
  const int m0 = blockIdx.x * 256;
  const int n0 = blockIdx.y * 128;
  const int t = threadIdx.x;
  const int ln = t & 63;
  const int w  = t >> 6;            // 0..7
  const int cl = ln & 15;
  const int qd = ln >> 4;
  const int wm = (w >> 1) * 64;     // 4 M-positions
  const int wn = (w & 1) * 64;      // 2 N-positions
  const int srow8 = ln >> 3;                         // 0..7
  const int sch   = (((ln & 7) ^ srow8) << 3);       // swizzled src chunk
  const int ch0   = ((qd ^ (cl & 7)) << 3);          // read-side chunk

  // 3 x (A 256x64 + B 128x64) bf16 = 144 KB
  __shared__ __align__(16) u16 Asm[3][256 * 64];
  __shared__ __align__(16) u16 Bsm[3][128 * 64];

  const f32x4 fzero = {0.f, 0.f, 0.f, 0.f};
  f32x4 acc[4][4];
#pragma unroll
  for (int i = 0; i < 4; ++i)
#pragma unroll
    for (int j = 0; j < 4; ++j) acc[i][j] = fzero;

  // stage K-tile kt (cols kt*64..) into buffer bi: 6 async16 per wave
  // (A: 4 instrs = rows w*32..w*32+31; B: 2 instrs = rows w*16..w*16+15)
  auto stage = [&](int kt, int bi) {
    const int k0 = kt * 64;
#pragma unroll
    for (int c = 0; c < 4; ++c)
      async16(X + (size_t)(m0 + w * 32 + c * 8 + srow8) * DD + k0 + sch,
              &Asm[bi][(w * 32 + c * 8) * 64]);
#pragma unroll
    for (int c = 0; c < 2; ++c)
      async16(Wt + (size_t)(n0 + w * 16 + c * 8 + srow8) * DD + k0 + sch,
              &Bsm[bi][(w * 16 + c * 8) * 64]);
  };

  stage(0, 0);   // prologue: tiles 0,1 in flight (12 loads/wave)
  stage(1, 1);

  const int NT = DD / 64;   // 16 K-tiles
  int cur = 0, pre = 2;     // pre = buffer for tile kt+2
  for (int kt = 0; kt < NT; ++kt) {
    // Counted wait: this wave's 6 loads for tile kt are the oldest of 12
    // outstanding -> vmcnt(6) completes tile kt, tile kt+1 stays in flight.
    if (kt + 1 < NT) {
      asm volatile("s_waitcnt vmcnt(6)" ::: "memory");
    } else {
      asm volatile("s_waitcnt vmcnt(0)" ::: "memory");
    }
    __builtin_amdgcn_s_barrier();     // all waves' tile-kt slices now done
    asm volatile("" ::: "memory");    // pin LDS reads below the barrier
    if (kt + 2 < NT) stage(kt + 2, pre);

    const u16* Ah = Asm[cur];
    const u16* Bh = Bsm[cur];

#pragma unroll
    for (int kk = 0; kk < 2; ++kk) {
      bf16x8 af[4], bf[4];
#pragma unroll
      for (int mb = 0; mb < 4; ++mb)
        af[mb] = *(const bf16x8*)&Ah[(wm + mb * 16 + cl) * 64 + (ch0 ^ (kk << 5))];
#pragma unroll
      for (int nb = 0; nb < 4; ++nb)
        bf[nb] = *(const bf16x8*)&Bh[(wn + nb * 16 + cl) * 64 + (ch0 ^ (kk << 5))];
      __builtin_amdgcn_s_setprio(1);
#pragma unroll
      for (int mb = 0; mb < 4; ++mb)
#pragma unroll
        for (int nb = 0; nb < 4; ++nb)
          acc[mb][nb] = MFMA16(af[mb], bf[nb], acc[mb][nb]);
      __builtin_amdgcn_s_setprio(0);
    }

    cur = (cur == 2) ? 0 : cur + 1;
    pre = (pre == 2) ? 0 : pre + 1;
  }

  const float scl = (z == 0) ? QSCALE : 1.0f;
#pragma unroll
  for (int mb = 0; mb < 4; ++mb) {
#pragma unroll
    for (int r = 0; r < 4; ++r) {
      const size_t row = (size_t)(m0 + wm + mb * 16 + qd * 4 + r) * DD;
      f32x4 v = {acc[mb][0][r] * scl, acc[mb][1][r] * scl,
                 acc[mb][2][r] * scl, acc[mb][3][r] * scl};
      bf16x4 bv = __builtin_convertvector(v, bf16x4);
#pragma unroll
      for (int nb = 0; nb < 4; ++nb)
        *(__bf16*)&Y[row + n0 + wn + nb * 16 + cl] = bv[nb];
    }
  }
}

// ---------------------------------------------------------------------------
// Kernel 2b: V [MM][DD] -> VtG [b][h][d=64][s=2048], PV key permutation
// baked in: position p in each 32-key block holds key kappa(p);
// write position = kappa^-1(k) = ((k&15)>>2)*8+(k>>4)*4+(k&3).
// ---------------------------------------------------------------------------
__global__ __launch_bounds__(256) void vtrans(
    const u16* __restrict__ V, u16* __restrict__ VtG)
{
  const int b = blockIdx.z;
  const int h = blockIdx.y;
  const int s0 = blockIdx.x * 64;
  __shared__ u16 tile[64][65];
#pragma unroll
  for (int i = 0; i < 16; ++i) {
    int e = threadIdx.x + i * 256;
    int r = e >> 6, c = e & 63;
    tile[r][c] = V[(size_t)(b * SS + s0 + r) * DD + h * DH + c];
  }
  __syncthreads();
#pragma unroll
  for (int i = 0; i < 16; ++i) {
    int e = threadIdx.x + i * 256;
    int r = e >> 6, c = e & 63;
    int k = c & 31;
    int pos = (c & 32) + ((k & 15) >> 2) * 8 + (k >> 4) * 4 + (k & 3);
    VtG[((size_t)(b * HH + h) * DH + r) * SS + s0 + pos] = tile[c][r];
  }
}

// ---------------------------------------------------------------------------
// Kernel 3: flash attention (round-12 version, best measured 76.5 us;
// compute-issue-saturated at ~900 TF — the plain-HIP ladder ceiling).
// 256 q-rows/block, 4 q-sets/wave; P stays in registers (V key-permuted);
// K/V frags register-held across all 4 q-sets.
// ---------------------------------------------------------------------------
__global__ __launch_bounds__(256, 2) void attn_kernel(
    const u16* __restrict__ QKV, const u16* __restrict__ VtG,
    float* __restrict__ Out)
{
  const int bh = blockIdx.x;       // 0..63: b*16+h  (XCD-locality axis)
  const int b = bh >> 4;
  const int h = bh & 15;
  const int q0 = blockIdx.y * 256;
  const int t = threadIdx.x;
  const int ln = t & 63;
  const int w  = t >> 6;
  const int cl = ln & 15;
  const int qd = ln >> 4;
  const int srow = ln >> 2;
  // staging-side swizzled source chunk (u16 units)
  const int swz = (((ln & 3) ^ ((srow >> 1) & 3)) << 3);
  // read-side swizzled chunk (u16 units)
  const int sx = ((qd ^ ((cl >> 1) & 3)) << 3);

  const u16* Qg = QKV;
  const u16* Kg = QKV + (size_t)MM * DD;

  // u16 units: K buf0/1 @ 0/4096 | V buf0/1 @ 8192/12288  (32 KB total)
  __shared__ __align__(16) u16 smem[16384];

  const size_t qoff0 = (size_t)(b * SS + q0 + w * 16 + cl) * DD + h * DH;
  const bf16x8 qf0a = *(const bf16x8*)(Qg + qoff0 + qd * 8);
  const bf16x8 qf0b = *(const bf16x8*)(Qg + qoff0 + 32 + qd * 8);
  const bf16x8 qf1a = *(const bf16x8*)(Qg + qoff0 + (size_t)64 * DD + qd * 8);
  const bf16x8 qf1b = *(const bf16x8*)(Qg + qoff0 + (size_t)64 * DD + 32 + qd * 8);
  const bf16x8 qf2a = *(const bf16x8*)(Qg + qoff0 + (size_t)128 * DD + qd * 8);
  const bf16x8 qf2b = *(const bf16x8*)(Qg + qoff0 + (size_t)128 * DD + 32 + qd * 8);
  const bf16x8 qf3a = *(const bf16x8*)(Qg + qoff0 + (size_t)192 * DD + qd * 8);
  const bf16x8 qf3b = *(const bf16x8*)(Qg + qoff0 + (size_t)192 * DD + 32 + qd * 8);

  const f32x4 fzero = {0.f, 0.f, 0.f, 0.f};
  f32x4 oacc0[4], oacc1[4], oacc2[4], oacc3[4];
#pragma unroll
  for (int mt = 0; mt < 4; ++mt) {
    oacc0[mt] = fzero; oacc1[mt] = fzero; oacc2[mt] = fzero; oacc3[mt] = fzero;
  }
  float lsum0 = 0.f, lsum1 = 0.f, lsum2 = 0.f, lsum3 = 0.f;

  const size_t kgbase  = (size_t)b * SS * DD + (size_t)h * DH;
  const size_t vtgbase = ((size_t)(b * HH + h)) * DH * SS;

  // stage K/V tile kt into buffer bi (16 async16 per block).
  auto stage = [&](int kt, int bi) {
    u16* kb = smem + bi * 4096;
    u16* vb = smem + 8192 + bi * 4096;
#pragma unroll
    for (int s = 0; s < 2; ++s) {
      async16(Kg  + kgbase + (size_t)(kt + w * 16 + srow) * DD + s * 32 + swz,
              kb + (s * 64 + w * 16) * 32);
      async16(VtG + vtgbase + (size_t)(w * 16 + srow) * SS + kt + s * 32 + swz,
              vb + (s * 64 + w * 16) * 32);
    }
  };

  // One q-set pair; P stays entirely in registers (V is key-permuted so the
  // B-frag slot (qd,j) wants exactly exp2(st[j>>2][j&3]) from this lane).
#define PAIR(QA0, QA1, QB0, QB1, OA, OB, LA, LB) do {                         \
    f32x4 stA[4], stB[4];                                                     \
    _Pragma("unroll")                                                         \
    for (int mt = 0; mt < 4; ++mt) {                                          \
      f32x4 za = fzero, zb = fzero;                                           \
      za = MFMA16(kf0[mt], QA0, za); za = MFMA16(kf1[mt], QA1, za);           \
      zb = MFMA16(kf0[mt], QB0, zb); zb = MFMA16(kf1[mt], QB1, zb);           \
      stA[mt] = za; stB[mt] = zb;                                             \
    }                                                                         \
    f32x4 pa0, pa1, pa2, pa3;                                                 \
    _Pragma("unroll")                                                         \
    for (int r = 0; r < 4; ++r) {                                             \
      pa0[r] = __builtin_amdgcn_exp2f(stA[0][r]); LA += pa0[r];               \
      pa1[r] = __builtin_amdgcn_exp2f(stA[1][r]); LA += pa1[r];               \
      pa2[r] = __builtin_amdgcn_exp2f(stA[2][r]); LA += pa2[r];               \
      pa3[r] = __builtin_amdgcn_exp2f(stA[3][r]); LA += pa3[r];               \
    }                                                                         \
    {                                                                         \
      bf16x8 pf0 = __builtin_shufflevector(                                   \
          __builtin_convertvector(pa0, bf16x4),                               \
          __builtin_convertvector(pa1, bf16x4), 0, 1, 2, 3, 4, 5, 6, 7);      \
      bf16x8 pf1 = __builtin_shufflevector(                                   \
          __builtin_convertvector(pa2, bf16x4),                               \
          __builtin_convertvector(pa3, bf16x4), 0, 1, 2, 3, 4, 5, 6, 7);      \
      _Pragma("unroll")                                                       \
      for (int mt = 0; mt < 4; ++mt) {                                        \
        OA[mt] = MFMA16(vf0[mt], pf0, OA[mt]);                                \
        OA[mt] = MFMA16(vf1[mt], pf1, OA[mt]);                                \
      }                                                                       \
    }                                                                         \
    f32x4 pb0, pb1, pb2, pb3;                                                 \
    _Pragma("unroll")                                                         \
    for (int r = 0; r < 4; ++r) {                                             \
      pb0[r] = __builtin_amdgcn_exp2f(stB[0][r]); LB += pb0[r];               \
      pb1[r] = __builtin_amdgcn_exp2f(stB[1][r]); LB += pb1[r];               \
      pb2[r] = __builtin_amdgcn_exp2f(stB[2][r]); LB += pb2[r];               \
      pb3[r] = __builtin_amdgcn_exp2f(stB[3][r]); LB += pb3[r];               \
    }                                                                         \
    {                                                                         \
      bf16x8 pf0 = __builtin_shufflevector(                                   \
          __builtin_convertvector(pb0, bf16x4),                               \
          __builtin_convertvector(pb1, bf16x4), 0, 1, 2, 3, 4, 5, 6, 7);      \
      bf16x8 pf1 = __builtin_shufflevector(                                   \
          __builtin_convertvector(pb2, bf16x4),                               \
          __builtin_convertvector(pb3, bf16x4), 0, 1, 2, 3, 4, 5, 6, 7);      \
      _Pragma("unroll")                                                       \
      for (int mt = 0; mt < 4; ++mt) {                                        \
        OB[mt] = MFMA16(vf0[mt], pf0, OB[mt]);                                \
        OB[mt] = MFMA16(vf1[mt], pf1, OB[mt]);                                \
      }                                                                       \
    }                                                                         \
  } while (0)

  stage(0, 0);   // prologue

  for (int it = 0; it < SS / 64; ++it) {
    const int cur = it & 1;
    // Drain this wave's outstanding LDS-DMA (the prefetch of buf[cur]),
    // THEN barrier to publish cross-wave + protect the WAR on buf[cur^1].
    WAIT_VM0();
    __syncthreads();
    if (it + 1 < SS / 64) stage((it + 1) * 64, cur ^ 1);

    const u16* Kh = smem + cur * 4096;
    const u16* Vh = smem + 8192 + cur * 4096;

    // K and V frags read once (swizzled), register-held for all 4 q-sets
    bf16x8 kf0[4], kf1[4], vf0[4], vf1[4];
#pragma unroll
    for (int mt = 0; mt < 4; ++mt) {
      kf0[mt] = *(const bf16x8*)&Kh[(mt * 16 + cl) * 32 + sx];
      kf1[mt] = *(const bf16x8*)&Kh[(64 + mt * 16 + cl) * 32 + sx];
      vf0[mt] = *(const bf16x8*)&Vh[(mt * 16 + cl) * 32 + sx];
      vf1[mt] = *(const bf16x8*)&Vh[(64 + mt * 16 + cl) * 32 + sx];
    }

    PAIR(qf0a, qf0b, qf1a, qf1b, oacc0, oacc1, lsum0, lsum1);
    PAIR(qf2a, qf2b, qf3a, qf3b, oacc2, oacc3, lsum2, lsum3);
  }

  // cross-lane normalizer reduction (once)
  lsum0 += __shfl_xor(lsum0, 16); lsum0 += __shfl_xor(lsum0, 32);
  lsum1 += __shfl_xor(lsum1, 16); lsum1 += __shfl_xor(lsum1, 32);
  lsum2 += __shfl_xor(lsum2, 16); lsum2 += __shfl_xor(lsum2, 32);
  lsum3 += __shfl_xor(lsum3, 16); lsum3 += __shfl_xor(lsum3, 32);

  // epilogue: normalize, transpose O^T -> O via per-wave LDS slab, store fp32
  __syncthreads();
  float* Ol = (float*)smem;        // per-wave slab: 1088 floats (17408 B tot)
  const int q   = ln >> 2;
  const int seg = ln & 3;
  const float* src = Ol + w * 1088 + q * 68 + seg * 16;

#define EPI(OA, LS, SOFF) do {                                                \
    const float inv = 1.f / (LS);                                             \
    _Pragma("unroll")                                                         \
    for (int mt = 0; mt < 4; ++mt) {                                          \
      f32x4 vv = OA[mt];                                                      \
      _Pragma("unroll")                                                       \
      for (int r = 0; r < 4; ++r) vv[r] *= inv;                               \
      *(f32x4*)(Ol + w * 1088 + cl * 68 + mt * 16 + qd * 4) = vv;             \
    }                                                                         \
    {                                                                         \
      float* dst = Out + (size_t)(b * SS + q0 + (SOFF) + w * 16 + q) * DD     \
                       + h * DH + seg * 16;                                   \
      _Pragma("unroll")                                                       \
      for (int i = 0; i < 4; ++i)                                             \
        *(f32x4*)(dst + i * 4) = *(const f32x4*)(src + i * 4);                \
    }                                                                         \
  } while (0)

  EPI(oacc0, lsum0, 0);
  EPI(oacc1, lsum1, 64);
  EPI(oacc2, lsum2, 128);
  EPI(oacc3, lsum3, 192);

#undef EPI
#undef PAIR
}

// ---------------------------------------------------------------------------
extern "C" void kernel_launch(void* const* d_in, const int* in_sizes, int n_in,
                              void* d_out, int out_size, void* d_ws, size_t ws_size,
                              hipStream_t stream)
{
  const float* x  = (const float*)d_in[0];
  const float* wq = (const float*)d_in[1];
  const float* wk = (const float*)d_in[2];
  const float* wv = (const float*)d_in[3];
  float* out = (float*)d_out;

  // ws (bf16): xs 16MB | wt 6MB | qkv 48MB | vtg 16MB = 86MB
  const size_t need = ((size_t)MM * DD + 3 * (size_t)DD * DD +
                       3 * (size_t)MM * DD + (size_t)MM * DD) * sizeof(u16);
  if (ws_size < need) {
    fill_sig<<<1024, 256, 0, stream>>>(out, out_size);
    return;
  }

  u16* xs  = (u16*)d_ws;
  u16* wt  = xs + (size_t)MM * DD;
  u16* qkv = wt + (size_t)3 * DD * DD;
  u16* vtg = qkv + (size_t)3 * MM * DD;

  convert_x<<<2048, 256, 0, stream>>>(x, xs);
  convert_w<<<dim3(16, 16, 3), 256, 0, stream>>>(wq, wk, wv, wt);
  // 256x128 tiles, 512 threads: 32 m-tiles x 8 n-tiles x 3 = 768 blocks
  qkv_gemm<<<dim3(32, 8, 3), 512, 0, stream>>>(xs, wt, qkv);
  vtrans<<<dim3(32, HH, BB), 256, 0, stream>>>(qkv + (size_t)2 * MM * DD, vtg);
  // grid.x = (b,h): XCD-local K/V; grid.y = q-block (256 rows/block)
  attn_kernel<<<dim3(HH * BB, SS / 256, 1), 256, 0, stream>>>(qkv, vtg, out);
}

// Round 8
// 220.350 us; speedup vs baseline: 1.0645x; 1.0645x over previous
//
#include <hip/hip_runtime.h>

typedef unsigned short u16;
typedef unsigned int   u32;
typedef __bf16 bf16x8 __attribute__((ext_vector_type(8)));
typedef __bf16 bf16x4 __attribute__((ext_vector_type(4)));
typedef float  f32x4  __attribute__((ext_vector_type(4)));
typedef u32    u32x4  __attribute__((ext_vector_type(4)));
typedef u32    u32x2  __attribute__((ext_vector_type(2)));
typedef u16    u16x8  __attribute__((ext_vector_type(8)));

#define MFMA16(a,b,c) __builtin_amdgcn_mfma_f32_16x16x32_bf16(a,b,c,0,0,0)

#define BB 4
#define SS 2048
#define DD 1024
#define HH 16
#define DH 64
#define MM 8192   // B*S

#define QSCALE 0.0901684400555602f   // (1/16) * log2(e), folded into Q

// s_waitcnt vmcnt(0) ONLY (expcnt=7, lgkmcnt=0xF masked off): gfx9 encoding
#define WAIT_VM0() __builtin_amdgcn_s_waitcnt(0x0F70)

__device__ __forceinline__ u16 f2bf(float f) {
  u32 u = __builtin_bit_cast(u32, f);
  u += 0x7fffu + ((u >> 16) & 1u);   // RNE
  return (u16)(u >> 16);
}

// async global->LDS DMA, 16B per lane. LDS dest = wave-uniform base + lane*16.
__device__ __forceinline__ void async16(const void* g, void* l) {
  __builtin_amdgcn_global_load_lds(
      (const __attribute__((address_space(1))) unsigned int*)g,
      (__attribute__((address_space(3))) unsigned int*)l, 16, 0, 0);
}

__global__ __launch_bounds__(256) void fill_sig(float* __restrict__ out, int n)
{
  for (int i = blockIdx.x * 256 + threadIdx.x; i < n; i += gridDim.x * 256)
    out[i] = 3.0f;
}

// ---------------------------------------------------------------------------
// Kernel 0 (merged): z=0..2 -> W[z] fp32 [K][N] -> Wt bf16 [N][K] tiles;
// z=3 -> x fp32 -> bf16 grid-stride (256 blocks). Saves one launch.
// ---------------------------------------------------------------------------
__global__ __launch_bounds__(256) void prep(
    const float* __restrict__ x,
    const float* __restrict__ w0, const float* __restrict__ w1,
    const float* __restrict__ w2,
    u16* __restrict__ xs, u16* __restrict__ WtAll)
{
  const int z = blockIdx.z;
  __shared__ u16 tile[64][65];
  if (z == 3) {
    const int blk = blockIdx.x + blockIdx.y * 16;          // 0..255
    const size_t stride = (size_t)256 * 256 * 8;
    for (size_t i = ((size_t)blk * 256 + threadIdx.x) * 8;
         i < (size_t)MM * DD; i += stride) {
      f32x4 a = *(const f32x4*)(x + i);
      f32x4 b = *(const f32x4*)(x + i + 4);
      u32x2 ua = __builtin_bit_cast(u32x2, __builtin_convertvector(a, bf16x4));
      u32x2 ub = __builtin_bit_cast(u32x2, __builtin_convertvector(b, bf16x4));
      u32x4 v = {ua[0], ua[1], ub[0], ub[1]};
      *(u32x4*)(xs + i) = v;
    }
    return;
  }
  const float* W = (z == 0) ? w0 : ((z == 1) ? w1 : w2);
  u16* Wt = WtAll + (size_t)z * DD * DD;
  const int n0 = blockIdx.x * 64;
  const int k0 = blockIdx.y * 64;
#pragma unroll
  for (int i = 0; i < 16; ++i) {
    int e = threadIdx.x + i * 256;
    int r = e >> 6, c = e & 63;
    tile[r][c] = f2bf(W[(size_t)(k0 + r) * DD + n0 + c]);
  }
  __syncthreads();
#pragma unroll
  for (int i = 0; i < 16; ++i) {
    int e = threadIdx.x + i * 256;
    int r = e >> 6, c = e & 63;
    Wt[(size_t)(n0 + r) * DD + k0 + c] = tile[c][r];
  }
}

// ---------------------------------------------------------------------------
// Kernel 1: QKV GEMM — round-4 PROVEN structure (128x128 tile, BK=64,
// chunk-XOR swizzle, double-buffered K-loop, 64 KB LDS, 2 blocks/CU).
// Round-18 change: FUSED V-TRANSPOSE EPILOGUE. For z==2 the epilogue writes
// VtG[b][h][d][s-perm] directly (per-wave 64x64 LDS slab transpose with the
// PV key-permutation kappa baked into the slab slot), skipping the Y write
// and the separate vtrans kernel entirely.
//   slot(s) for s = S0+wm+mb*16+qd*4+r:  (mb>>1)*32 + qd*8 + (mb&1)*4 + r
//   (derivation: kappa^-1(k)=((k&15)>>2)*8+(k>>4)*4+(k&3), k=s&31)
// ---------------------------------------------------------------------------
__global__ __launch_bounds__(256) void qkv_gemm(
    const u16* __restrict__ X, const u16* __restrict__ WtAll,
    u16* __restrict__ QKV, u16* __restrict__ VtG)
{
  const int z = blockIdx.z;
  const u16* Wt = WtAll + (size_t)z * DD * DD;
  u16* Y = QKV + (size_t)z * MM * DD;
  const int m0 = blockIdx.x * 128;
  const int n0 = blockIdx.y * 128;
  const int t = threadIdx.x;
  const int ln = t & 63;
  const int w  = t >> 6;
  const int cl = ln & 15;
  const int qd = ln >> 4;
  const int wm = (w & 1) * 64;
  const int wn = (w >> 1) * 64;
  const int srow8 = ln >> 3;                              // 8 rows/wave-round
  const int sch   = (((ln & 7) ^ (srow8 & 7)) << 3);      // swizzled src chunk
  const int ch0   = ((qd ^ (cl & 7)) << 3);               // read-side chunk

  __shared__ __align__(16) u16 Asm[2][128 * 64];
  __shared__ __align__(16) u16 Bsm[2][128 * 64];

  const f32x4 fzero = {0.f, 0.f, 0.f, 0.f};
  f32x4 acc[4][4];
#pragma unroll
  for (int i = 0; i < 4; ++i)
#pragma unroll
    for (int j = 0; j < 4; ++j) acc[i][j] = fzero;

  // stage K-tile starting at k0 into buffer bi (8 async16 per wave)
  auto stage = [&](int k0, int bi) {
#pragma unroll
    for (int c = 0; c < 4; ++c) {
      async16(X  + (size_t)(m0 + c * 32 + w * 8 + srow8) * DD + k0 + sch,
              &Asm[bi][(c * 32 + w * 8) * 64]);
      async16(Wt + (size_t)(n0 + c * 32 + w * 8 + srow8) * DD + k0 + sch,
              &Bsm[bi][(c * 32 + w * 8) * 64]);
    }
  };

  stage(0, 0);   // prologue

  for (int k0 = 0; k0 < DD; k0 += 64) {
    const int cur = (k0 >> 6) & 1;
    // Drain this wave's outstanding LDS-DMA (prefetch of buf[cur], issued
    // last iteration), THEN barrier: publishes buf[cur] cross-wave and
    // protects the WAR on buf[cur^1] (all waves done reading it).
    WAIT_VM0();
    __syncthreads();
    if (k0 + 64 < DD) stage(k0 + 64, cur ^ 1);

    const u16* Ah = Asm[cur];
    const u16* Bh = Bsm[cur];

#pragma unroll
    for (int kk = 0; kk < 2; ++kk) {
      bf16x8 af[4], bf[4];
#pragma unroll
      for (int mb = 0; mb < 4; ++mb)
        af[mb] = *(const bf16x8*)&Ah[(wm + mb * 16 + cl) * 64 + (ch0 ^ (kk << 5))];
#pragma unroll
      for (int nb = 0; nb < 4; ++nb)
        bf[nb] = *(const bf16x8*)&Bh[(wn + nb * 16 + cl) * 64 + (ch0 ^ (kk << 5))];
#pragma unroll
      for (int mb = 0; mb < 4; ++mb)
#pragma unroll
        for (int nb = 0; nb < 4; ++nb)
          acc[mb][nb] = MFMA16(af[mb], bf[nb], acc[mb][nb]);
    }
  }

  if (z < 2) {
    // Q (scaled) / K: plain row-major store to QKV
    const float scl = (z == 0) ? QSCALE : 1.0f;
#pragma unroll
    for (int mb = 0; mb < 4; ++mb) {
#pragma unroll
      for (int r = 0; r < 4; ++r) {
        const size_t row = (size_t)(m0 + wm + mb * 16 + qd * 4 + r) * DD;
        f32x4 v = {acc[mb][0][r] * scl, acc[mb][1][r] * scl,
                   acc[mb][2][r] * scl, acc[mb][3][r] * scl};
        bf16x4 bv = __builtin_convertvector(v, bf16x4);
#pragma unroll
        for (int nb = 0; nb < 4; ++nb)
          *(__bf16*)&Y[row + n0 + wn + nb * 16 + cl] = bv[nb];
      }
    }
  } else {
    // V: transpose + kappa-permute into VtG via per-wave 8 KB LDS slab.
    __syncthreads();                      // all waves done reading Asm/Bsm
    u16* slab = (u16*)Asm + w * 4096;     // 4 waves x 4096 u16 = 32 KB
    const int bb = m0 >> 11;              // wave-uniform batch
    const int hh = (n0 + wn) >> 6;        // wave-uniform head
    const int S0 = m0 - bb * SS + wm;     // tile s-base (64-aligned)
#pragma unroll
    for (int mb = 0; mb < 4; ++mb) {
      const int sp = (mb >> 1) * 32 + qd * 8 + (mb & 1) * 4;
#pragma unroll
      for (int nb = 0; nb < 4; ++nb) {
        f32x4 v = {acc[mb][nb][0], acc[mb][nb][1],
                   acc[mb][nb][2], acc[mb][nb][3]};
        bf16x4 bv = __builtin_convertvector(v, bf16x4);
        *(bf16x4*)&slab[(nb * 16 + cl) * 64 + sp] = bv;   // d-major slab
      }
    }
    // same-wave DS in-order: compiler inserts lgkmcnt before readback
    const size_t vbase = ((size_t)(bb * HH + hh)) * DH * SS;
#pragma unroll
    for (int i = 0; i < 8; ++i) {
      const int dr = (ln >> 3) + i * 8;
      const u16x8 vv = *(const u16x8*)&slab[dr * 64 + (ln & 7) * 8];
      *(u16x8*)(VtG + vbase + (size_t)dr * SS + S0 + (ln & 7) * 8) = vv;
    }
  }
}

// ---------------------------------------------------------------------------
// Kernel 2: flash attention (round-12 version, best measured 76.5 us;
// compute-issue-saturated at ~900 TF — the plain-HIP ladder ceiling).
// 256 q-rows/block, 4 q-sets/wave; P stays in registers (V key-permuted);
// K/V frags register-held across all 4 q-sets.
// ---------------------------------------------------------------------------
__global__ __launch_bounds__(256, 2) void attn_kernel(
    const u16* __restrict__ QKV, const u16* __restrict__ VtG,
    float* __restrict__ Out)
{
  const int bh = blockIdx.x;       // 0..63: b*16+h  (XCD-locality axis)
  const int b = bh >> 4;
  const int h = bh & 15;
  const int q0 = blockIdx.y * 256;
  const int t = threadIdx.x;
  const int ln = t & 63;
  const int w  = t >> 6;
  const int cl = ln & 15;
  const int qd = ln >> 4;
  const int srow = ln >> 2;
  // staging-side swizzled source chunk (u16 units)
  const int swz = (((ln & 3) ^ ((srow >> 1) & 3)) << 3);
  // read-side swizzled chunk (u16 units)
  const int sx = ((qd ^ ((cl >> 1) & 3)) << 3);

  const u16* Qg = QKV;
  const u16* Kg = QKV + (size_t)MM * DD;

  // u16 units: K buf0/1 @ 0/4096 | V buf0/1 @ 8192/12288  (32 KB total)
  __shared__ __align__(16) u16 smem[16384];

  const size_t qoff0 = (size_t)(b * SS + q0 + w * 16 + cl) * DD + h * DH;
  const bf16x8 qf0a = *(const bf16x8*)(Qg + qoff0 + qd * 8);
  const bf16x8 qf0b = *(const bf16x8*)(Qg + qoff0 + 32 + qd * 8);
  const bf16x8 qf1a = *(const bf16x8*)(Qg + qoff0 + (size_t)64 * DD + qd * 8);
  const bf16x8 qf1b = *(const bf16x8*)(Qg + qoff0 + (size_t)64 * DD + 32 + qd * 8);
  const bf16x8 qf2a = *(const bf16x8*)(Qg + qoff0 + (size_t)128 * DD + qd * 8);
  const bf16x8 qf2b = *(const bf16x8*)(Qg + qoff0 + (size_t)128 * DD + 32 + qd * 8);
  const bf16x8 qf3a = *(const bf16x8*)(Qg + qoff0 + (size_t)192 * DD + qd * 8);
  const bf16x8 qf3b = *(const bf16x8*)(Qg + qoff0 + (size_t)192 * DD + 32 + qd * 8);

  const f32x4 fzero = {0.f, 0.f, 0.f, 0.f};
  f32x4 oacc0[4], oacc1[4], oacc2[4], oacc3[4];
#pragma unroll
  for (int mt = 0; mt < 4; ++mt) {
    oacc0[mt] = fzero; oacc1[mt] = fzero; oacc2[mt] = fzero; oacc3[mt] = fzero;
  }
  float lsum0 = 0.f, lsum1 = 0.f, lsum2 = 0.f, lsum3 = 0.f;

  const size_t kgbase  = (size_t)b * SS * DD + (size_t)h * DH;
  const size_t vtgbase = ((size_t)(b * HH + h)) * DH * SS;

  // stage K/V tile kt into buffer bi (16 async16 per block).
  auto stage = [&](int kt, int bi) {
    u16* kb = smem + bi * 4096;
    u16* vb = smem + 8192 + bi * 4096;
#pragma unroll
    for (int s = 0; s < 2; ++s) {
      async16(Kg  + kgbase + (size_t)(kt + w * 16 + srow) * DD + s * 32 + swz,
              kb + (s * 64 + w * 16) * 32);
      async16(VtG + vtgbase + (size_t)(w * 16 + srow) * SS + kt + s * 32 + swz,
              vb + (s * 64 + w * 16) * 32);
    }
  };

  // One q-set pair; P stays entirely in registers (V is key-permuted so the
  // B-frag slot (qd,j) wants exactly exp2(st[j>>2][j&3]) from this lane).
#define PAIR(QA0, QA1, QB0, QB1, OA, OB, LA, LB) do {                         \
    f32x4 stA[4], stB[4];                                                     \
    _Pragma("unroll")                                                         \
    for (int mt = 0; mt < 4; ++mt) {                                          \
      f32x4 za = fzero, zb = fzero;                                           \
      za = MFMA16(kf0[mt], QA0, za); za = MFMA16(kf1[mt], QA1, za);           \
      zb = MFMA16(kf0[mt], QB0, zb); zb = MFMA16(kf1[mt], QB1, zb);           \
      stA[mt] = za; stB[mt] = zb;                                             \
    }                                                                         \
    f32x4 pa0, pa1, pa2, pa3;                                                 \
    _Pragma("unroll")                                                         \
    for (int r = 0; r < 4; ++r) {                                             \
      pa0[r] = __builtin_amdgcn_exp2f(stA[0][r]); LA += pa0[r];               \
      pa1[r] = __builtin_amdgcn_exp2f(stA[1][r]); LA += pa1[r];               \
      pa2[r] = __builtin_amdgcn_exp2f(stA[2][r]); LA += pa2[r];               \
      pa3[r] = __builtin_amdgcn_exp2f(stA[3][r]); LA += pa3[r];               \
    }                                                                         \
    {                                                                         \
      bf16x8 pf0 = __builtin_shufflevector(                                   \
          __builtin_convertvector(pa0, bf16x4),                               \
          __builtin_convertvector(pa1, bf16x4), 0, 1, 2, 3, 4, 5, 6, 7);      \
      bf16x8 pf1 = __builtin_shufflevector(                                   \
          __builtin_convertvector(pa2, bf16x4),                               \
          __builtin_convertvector(pa3, bf16x4), 0, 1, 2, 3, 4, 5, 6, 7);      \
      _Pragma("unroll")                                                       \
      for (int mt = 0; mt < 4; ++mt) {                                        \
        OA[mt] = MFMA16(vf0[mt], pf0, OA[mt]);                                \
        OA[mt] = MFMA16(vf1[mt], pf1, OA[mt]);                                \
      }                                                                       \
    }                                                                         \
    f32x4 pb0, pb1, pb2, pb3;                                                 \
    _Pragma("unroll")                                                         \
    for (int r = 0; r < 4; ++r) {                                             \
      pb0[r] = __builtin_amdgcn_exp2f(stB[0][r]); LB += pb0[r];               \
      pb1[r] = __builtin_amdgcn_exp2f(stB[1][r]); LB += pb1[r];               \
      pb2[r] = __builtin_amdgcn_exp2f(stB[2][r]); LB += pb2[r];               \
      pb3[r] = __builtin_amdgcn_exp2f(stB[3][r]); LB += pb3[r];               \
    }                                                                         \
    {                                                                         \
      bf16x8 pf0 = __builtin_shufflevector(                                   \
          __builtin_convertvector(pb0, bf16x4),                               \
          __builtin_convertvector(pb1, bf16x4), 0, 1, 2, 3, 4, 5, 6, 7);      \
      bf16x8 pf1 = __builtin_shufflevector(                                   \
          __builtin_convertvector(pb2, bf16x4),                               \
          __builtin_convertvector(pb3, bf16x4), 0, 1, 2, 3, 4, 5, 6, 7);      \
      _Pragma("unroll")                                                       \
      for (int mt = 0; mt < 4; ++mt) {                                        \
        OB[mt] = MFMA16(vf0[mt], pf0, OB[mt]);                                \
        OB[mt] = MFMA16(vf1[mt], pf1, OB[mt]);                                \
      }                                                                       \
    }                                                                         \
  } while (0)

  stage(0, 0);   // prologue

  for (int it = 0; it < SS / 64; ++it) {
    const int cur = it & 1;
    // Drain this wave's outstanding LDS-DMA (the prefetch of buf[cur]),
    // THEN barrier to publish cross-wave + protect the WAR on buf[cur^1].
    WAIT_VM0();
    __syncthreads();
    if (it + 1 < SS / 64) stage((it + 1) * 64, cur ^ 1);

    const u16* Kh = smem + cur * 4096;
    const u16* Vh = smem + 8192 + cur * 4096;

    // K and V frags read once (swizzled), register-held for all 4 q-sets
    bf16x8 kf0[4], kf1[4], vf0[4], vf1[4];
#pragma unroll
    for (int mt = 0; mt < 4; ++mt) {
      kf0[mt] = *(const bf16x8*)&Kh[(mt * 16 + cl) * 32 + sx];
      kf1[mt] = *(const bf16x8*)&Kh[(64 + mt * 16 + cl) * 32 + sx];
      vf0[mt] = *(const bf16x8*)&Vh[(mt * 16 + cl) * 32 + sx];
      vf1[mt] = *(const bf16x8*)&Vh[(64 + mt * 16 + cl) * 32 + sx];
    }

    PAIR(qf0a, qf0b, qf1a, qf1b, oacc0, oacc1, lsum0, lsum1);
    PAIR(qf2a, qf2b, qf3a, qf3b, oacc2, oacc3, lsum2, lsum3);
  }

  // cross-lane normalizer reduction (once)
  lsum0 += __shfl_xor(lsum0, 16); lsum0 += __shfl_xor(lsum0, 32);
  lsum1 += __shfl_xor(lsum1, 16); lsum1 += __shfl_xor(lsum1, 32);
  lsum2 += __shfl_xor(lsum2, 16); lsum2 += __shfl_xor(lsum2, 32);
  lsum3 += __shfl_xor(lsum3, 16); lsum3 += __shfl_xor(lsum3, 32);

  // epilogue: normalize, transpose O^T -> O via per-wave LDS slab, store fp32
  __syncthreads();
  float* Ol = (float*)smem;        // per-wave slab: 1088 floats (17408 B tot)
  const int q   = ln >> 2;
  const int seg = ln & 3;
  const float* src = Ol + w * 1088 + q * 68 + seg * 16;

#define EPI(OA, LS, SOFF) do {                                                \
    const float inv = 1.f / (LS);                                             \
    _Pragma("unroll")                                                         \
    for (int mt = 0; mt < 4; ++mt) {                                          \
      f32x4 vv = OA[mt];                                                      \
      _Pragma("unroll")                                                       \
      for (int r = 0; r < 4; ++r) vv[r] *= inv;                               \
      *(f32x4*)(Ol + w * 1088 + cl * 68 + mt * 16 + qd * 4) = vv;             \
    }                                                                         \
    {                                                                         \
      float* dst = Out + (size_t)(b * SS + q0 + (SOFF) + w * 16 + q) * DD     \
                       + h * DH + seg * 16;                                   \
      _Pragma("unroll")                                                       \
      for (int i = 0; i < 4; ++i)                                             \
        *(f32x4*)(dst + i * 4) = *(const f32x4*)(src + i * 4);                \
    }                                                                         \
  } while (0)

  EPI(oacc0, lsum0, 0);
  EPI(oacc1, lsum1, 64);
  EPI(oacc2, lsum2, 128);
  EPI(oacc3, lsum3, 192);

#undef EPI
#undef PAIR
}

// ---------------------------------------------------------------------------
extern "C" void kernel_launch(void* const* d_in, const int* in_sizes, int n_in,
                              void* d_out, int out_size, void* d_ws, size_t ws_size,
                              hipStream_t stream)
{
  const float* x  = (const float*)d_in[0];
  const float* wq = (const float*)d_in[1];
  const float* wk = (const float*)d_in[2];
  const float* wv = (const float*)d_in[3];
  float* out = (float*)d_out;

  // ws (bf16): xs 16MB | wt 6MB | qkv 48MB | vtg 16MB = 86MB
  const size_t need = ((size_t)MM * DD + 3 * (size_t)DD * DD +
                       3 * (size_t)MM * DD + (size_t)MM * DD) * sizeof(u16);
  if (ws_size < need) {
    fill_sig<<<1024, 256, 0, stream>>>(out, out_size);
    return;
  }

  u16* xs  = (u16*)d_ws;
  u16* wt  = xs + (size_t)MM * DD;
  u16* qkv = wt + (size_t)3 * DD * DD;
  u16* vtg = qkv + (size_t)3 * MM * DD;

  // 3 launches total (was 5): prep (x-convert + W-transpose), qkv (+fused
  // V-transpose for z==2), attn.
  prep<<<dim3(16, 16, 4), 256, 0, stream>>>(x, wq, wk, wv, xs, wt);
  qkv_gemm<<<dim3(64, 8, 3), 256, 0, stream>>>(xs, wt, qkv, vtg);
  attn_kernel<<<dim3(HH * BB, SS / 256, 1), 256, 0, stream>>>(qkv, vtg, out);
}

// Round 9
// 217.857 us; speedup vs baseline: 1.0767x; 1.0114x over previous
//
#include <hip/hip_runtime.h>

typedef unsigned short u16;
typedef unsigned int   u32;
typedef __bf16 bf16x8 __attribute__((ext_vector_type(8)));
typedef __bf16 bf16x4 __attribute__((ext_vector_type(4)));
typedef float  f32x4  __attribute__((ext_vector_type(4)));
typedef u32    u32x4  __attribute__((ext_vector_type(4)));
typedef u32    u32x2  __attribute__((ext_vector_type(2)));
typedef u16    u16x8  __attribute__((ext_vector_type(8)));

#define MFMA16(a,b,c) __builtin_amdgcn_mfma_f32_16x16x32_bf16(a,b,c,0,0,0)

#define BB 4
#define SS 2048
#define DD 1024
#define HH 16
#define DH 64
#define MM 8192   // B*S

#define QSCALE 0.0901684400555602f   // (1/16) * log2(e), folded into Q

// s_waitcnt vmcnt(0) ONLY (expcnt=7, lgkmcnt=0xF masked off): gfx9 encoding
#define WAIT_VM0() __builtin_amdgcn_s_waitcnt(0x0F70)

__device__ __forceinline__ u16 f2bf(float f) {
  u32 u = __builtin_bit_cast(u32, f);
  u += 0x7fffu + ((u >> 16) & 1u);   // RNE
  return (u16)(u >> 16);
}

// async global->LDS DMA, 16B per lane. LDS dest = wave-uniform base + lane*16.
__device__ __forceinline__ void async16(const void* g, void* l) {
  __builtin_amdgcn_global_load_lds(
      (const __attribute__((address_space(1))) unsigned int*)g,
      (__attribute__((address_space(3))) unsigned int*)l, 16, 0, 0);
}

__global__ __launch_bounds__(256) void fill_sig(float* __restrict__ out, int n)
{
  for (int i = blockIdx.x * 256 + threadIdx.x; i < n; i += gridDim.x * 256)
    out[i] = 3.0f;
}

// ---------------------------------------------------------------------------
// Kernel 0: x fp32 -> bf16 (hw packed cvt). 2048 blocks (8/CU) — R8's merged
// 256-block version starved HBM issue (the round-8 regression).
// ---------------------------------------------------------------------------
__global__ __launch_bounds__(256) void convert_x(
    const float* __restrict__ in, u16* __restrict__ out)
{
  const size_t stride = (size_t)gridDim.x * 256 * 8;
  for (size_t i = ((size_t)blockIdx.x * 256 + threadIdx.x) * 8;
       i < (size_t)MM * DD; i += stride) {
    f32x4 a = *(const f32x4*)(in + i);
    f32x4 b = *(const f32x4*)(in + i + 4);
    u32x2 ua = __builtin_bit_cast(u32x2, __builtin_convertvector(a, bf16x4));
    u32x2 ub = __builtin_bit_cast(u32x2, __builtin_convertvector(b, bf16x4));
    u32x4 v = {ua[0], ua[1], ub[0], ub[1]};
    *(u32x4*)(out + i) = v;
  }
}

// ---------------------------------------------------------------------------
// Kernel 1: W fp32 [K][N] -> Wt bf16 [N][K]
// ---------------------------------------------------------------------------
__global__ __launch_bounds__(256) void convert_w(
    const float* __restrict__ w0, const float* __restrict__ w1,
    const float* __restrict__ w2, u16* __restrict__ WtAll)
{
  const int z = blockIdx.z;
  const float* W = (z == 0) ? w0 : ((z == 1) ? w1 : w2);
  u16* Wt = WtAll + (size_t)z * DD * DD;
  const int n0 = blockIdx.x * 64;
  const int k0 = blockIdx.y * 64;
  __shared__ u16 tile[64][65];
#pragma unroll
  for (int i = 0; i < 16; ++i) {
    int e = threadIdx.x + i * 256;
    int r = e >> 6, c = e & 63;
    tile[r][c] = f2bf(W[(size_t)(k0 + r) * DD + n0 + c]);
  }
  __syncthreads();
#pragma unroll
  for (int i = 0; i < 16; ++i) {
    int e = threadIdx.x + i * 256;
    int r = e >> 6, c = e & 63;
    Wt[(size_t)(n0 + r) * DD + k0 + c] = tile[c][r];
  }
}

// ---------------------------------------------------------------------------
// Kernel 2: QKV GEMM — round-4 PROVEN structure (128x128 tile, BK=64,
// chunk-XOR swizzle, double-buffered K-loop, 64 KB LDS, 2 blocks/CU) with
// the round-8 FUSED V-TRANSPOSE EPILOGUE (z==2 writes VtG directly with the
// kappa key-permutation; saves the separate vtrans kernel + 16 MB write).
//   slot(s) for s = S0+wm+mb*16+qd*4+r:  (mb>>1)*32 + qd*8 + (mb&1)*4 + r
// ---------------------------------------------------------------------------
__global__ __launch_bounds__(256) void qkv_gemm(
    const u16* __restrict__ X, const u16* __restrict__ WtAll,
    u16* __restrict__ QKV, u16* __restrict__ VtG)
{
  const int z = blockIdx.z;
  const u16* Wt = WtAll + (size_t)z * DD * DD;
  u16* Y = QKV + (size_t)z * MM * DD;
  const int m0 = blockIdx.x * 128;
  const int n0 = blockIdx.y * 128;
  const int t = threadIdx.x;
  const int ln = t & 63;
  const int w  = t >> 6;
  const int cl = ln & 15;
  const int qd = ln >> 4;
  const int wm = (w & 1) * 64;
  const int wn = (w >> 1) * 64;
  const int srow8 = ln >> 3;                              // 8 rows/wave-round
  const int sch   = (((ln & 7) ^ (srow8 & 7)) << 3);      // swizzled src chunk
  const int ch0   = ((qd ^ (cl & 7)) << 3);               // read-side chunk

  __shared__ __align__(16) u16 Asm[2][128 * 64];
  __shared__ __align__(16) u16 Bsm[2][128 * 64];

  const f32x4 fzero = {0.f, 0.f, 0.f, 0.f};
  f32x4 acc[4][4];
#pragma unroll
  for (int i = 0; i < 4; ++i)
#pragma unroll
    for (int j = 0; j < 4; ++j) acc[i][j] = fzero;

  // stage K-tile starting at k0 into buffer bi (8 async16 per wave)
  auto stage = [&](int k0, int bi) {
#pragma unroll
    for (int c = 0; c < 4; ++c) {
      async16(X  + (size_t)(m0 + c * 32 + w * 8 + srow8) * DD + k0 + sch,
              &Asm[bi][(c * 32 + w * 8) * 64]);
      async16(Wt + (size_t)(n0 + c * 32 + w * 8 + srow8) * DD + k0 + sch,
              &Bsm[bi][(c * 32 + w * 8) * 64]);
    }
  };

  stage(0, 0);   // prologue

  for (int k0 = 0; k0 < DD; k0 += 64) {
    const int cur = (k0 >> 6) & 1;
    // Drain this wave's outstanding LDS-DMA (prefetch of buf[cur], issued
    // last iteration), THEN barrier: publishes buf[cur] cross-wave and
    // protects the WAR on buf[cur^1] (all waves done reading it).
    WAIT_VM0();
    __syncthreads();
    if (k0 + 64 < DD) stage(k0 + 64, cur ^ 1);

    const u16* Ah = Asm[cur];
    const u16* Bh = Bsm[cur];

#pragma unroll
    for (int kk = 0; kk < 2; ++kk) {
      bf16x8 af[4], bf[4];
#pragma unroll
      for (int mb = 0; mb < 4; ++mb)
        af[mb] = *(const bf16x8*)&Ah[(wm + mb * 16 + cl) * 64 + (ch0 ^ (kk << 5))];
#pragma unroll
      for (int nb = 0; nb < 4; ++nb)
        bf[nb] = *(const bf16x8*)&Bh[(wn + nb * 16 + cl) * 64 + (ch0 ^ (kk << 5))];
#pragma unroll
      for (int mb = 0; mb < 4; ++mb)
#pragma unroll
        for (int nb = 0; nb < 4; ++nb)
          acc[mb][nb] = MFMA16(af[mb], bf[nb], acc[mb][nb]);
    }
  }

  if (z < 2) {
    // Q (scaled) / K: plain row-major store to QKV
    const float scl = (z == 0) ? QSCALE : 1.0f;
#pragma unroll
    for (int mb = 0; mb < 4; ++mb) {
#pragma unroll
      for (int r = 0; r < 4; ++r) {
        const size_t row = (size_t)(m0 + wm + mb * 16 + qd * 4 + r) * DD;
        f32x4 v = {acc[mb][0][r] * scl, acc[mb][1][r] * scl,
                   acc[mb][2][r] * scl, acc[mb][3][r] * scl};
        bf16x4 bv = __builtin_convertvector(v, bf16x4);
#pragma unroll
        for (int nb = 0; nb < 4; ++nb)
          *(__bf16*)&Y[row + n0 + wn + nb * 16 + cl] = bv[nb];
      }
    }
  } else {
    // V: transpose + kappa-permute into VtG via per-wave 8 KB LDS slab.
    __syncthreads();                      // all waves done reading Asm/Bsm
    u16* slab = (u16*)Asm + w * 4096;     // 4 waves x 4096 u16 = 32 KB
    const int bb = m0 >> 11;              // wave-uniform batch
    const int hh = (n0 + wn) >> 6;        // wave-uniform head
    const int S0 = m0 - bb * SS + wm;     // tile s-base (64-aligned)
#pragma unroll
    for (int mb = 0; mb < 4; ++mb) {
      const int sp = (mb >> 1) * 32 + qd * 8 + (mb & 1) * 4;
#pragma unroll
      for (int nb = 0; nb < 4; ++nb) {
        f32x4 v = {acc[mb][nb][0], acc[mb][nb][1],
                   acc[mb][nb][2], acc[mb][nb][3]};
        bf16x4 bv = __builtin_convertvector(v, bf16x4);
        *(bf16x4*)&slab[(nb * 16 + cl) * 64 + sp] = bv;   // d-major slab
      }
    }
    // same-wave DS in-order: compiler inserts lgkmcnt before readback
    const size_t vbase = ((size_t)(bb * HH + hh)) * DH * SS;
#pragma unroll
    for (int i = 0; i < 8; ++i) {
      const int dr = (ln >> 3) + i * 8;
      const u16x8 vv = *(const u16x8*)&slab[dr * 64 + (ln & 7) * 8];
      *(u16x8*)(VtG + vbase + (size_t)dr * SS + S0 + (ln & 7) * 8) = vv;
    }
  }
}

// ---------------------------------------------------------------------------
// Kernel 3: flash attention (round-12 version, best measured 76.5 us;
// compute-issue-saturated at ~900 TF — the plain-HIP ladder ceiling).
// 256 q-rows/block, 4 q-sets/wave; P stays in registers (V key-permuted);
// K/V frags register-held across all 4 q-sets.
// ---------------------------------------------------------------------------
__global__ __launch_bounds__(256, 2) void attn_kernel(
    const u16* __restrict__ QKV, const u16* __restrict__ VtG,
    float* __restrict__ Out)
{
  const int bh = blockIdx.x;       // 0..63: b*16+h  (XCD-locality axis)
  const int b = bh >> 4;
  const int h = bh & 15;
  const int q0 = blockIdx.y * 256;
  const int t = threadIdx.x;
  const int ln = t & 63;
  const int w  = t >> 6;
  const int cl = ln & 15;
  const int qd = ln >> 4;
  const int srow = ln >> 2;
  // staging-side swizzled source chunk (u16 units)
  const int swz = (((ln & 3) ^ ((srow >> 1) & 3)) << 3);
  // read-side swizzled chunk (u16 units)
  const int sx = ((qd ^ ((cl >> 1) & 3)) << 3);

  const u16* Qg = QKV;
  const u16* Kg = QKV + (size_t)MM * DD;

  // u16 units: K buf0/1 @ 0/4096 | V buf0/1 @ 8192/12288  (32 KB total)
  __shared__ __align__(16) u16 smem[16384];

  const size_t qoff0 = (size_t)(b * SS + q0 + w * 16 + cl) * DD + h * DH;
  const bf16x8 qf0a = *(const bf16x8*)(Qg + qoff0 + qd * 8);
  const bf16x8 qf0b = *(const bf16x8*)(Qg + qoff0 + 32 + qd * 8);
  const bf16x8 qf1a = *(const bf16x8*)(Qg + qoff0 + (size_t)64 * DD + qd * 8);
  const bf16x8 qf1b = *(const bf16x8*)(Qg + qoff0 + (size_t)64 * DD + 32 + qd * 8);
  const bf16x8 qf2a = *(const bf16x8*)(Qg + qoff0 + (size_t)128 * DD + qd * 8);
  const bf16x8 qf2b = *(const bf16x8*)(Qg + qoff0 + (size_t)128 * DD + 32 + qd * 8);
  const bf16x8 qf3a = *(const bf16x8*)(Qg + qoff0 + (size_t)192 * DD + qd * 8);
  const bf16x8 qf3b = *(const bf16x8*)(Qg + qoff0 + (size_t)192 * DD + 32 + qd * 8);

  const f32x4 fzero = {0.f, 0.f, 0.f, 0.f};
  f32x4 oacc0[4], oacc1[4], oacc2[4], oacc3[4];
#pragma unroll
  for (int mt = 0; mt < 4; ++mt) {
    oacc0[mt] = fzero; oacc1[mt] = fzero; oacc2[mt] = fzero; oacc3[mt] = fzero;
  }
  float lsum0 = 0.f, lsum1 = 0.f, lsum2 = 0.f, lsum3 = 0.f;

  const size_t kgbase  = (size_t)b * SS * DD + (size_t)h * DH;
  const size_t vtgbase = ((size_t)(b * HH + h)) * DH * SS;

  // stage K/V tile kt into buffer bi (16 async16 per block).
  auto stage = [&](int kt, int bi) {
    u16* kb = smem + bi * 4096;
    u16* vb = smem + 8192 + bi * 4096;
#pragma unroll
    for (int s = 0; s < 2; ++s) {
      async16(Kg  + kgbase + (size_t)(kt + w * 16 + srow) * DD + s * 32 + swz,
              kb + (s * 64 + w * 16) * 32);
      async16(VtG + vtgbase + (size_t)(w * 16 + srow) * SS + kt + s * 32 + swz,
              vb + (s * 64 + w * 16) * 32);
    }
  };

  // One q-set pair; P stays entirely in registers (V is key-permuted so the
  // B-frag slot (qd,j) wants exactly exp2(st[j>>2][j&3]) from this lane).
#define PAIR(QA0, QA1, QB0, QB1, OA, OB, LA, LB) do {                         \
    f32x4 stA[4], stB[4];                                                     \
    _Pragma("unroll")                                                         \
    for (int mt = 0; mt < 4; ++mt) {                                          \
      f32x4 za = fzero, zb = fzero;                                           \
      za = MFMA16(kf0[mt], QA0, za); za = MFMA16(kf1[mt], QA1, za);           \
      zb = MFMA16(kf0[mt], QB0, zb); zb = MFMA16(kf1[mt], QB1, zb);           \
      stA[mt] = za; stB[mt] = zb;                                             \
    }                                                                         \
    f32x4 pa0, pa1, pa2, pa3;                                                 \
    _Pragma("unroll")                                                         \
    for (int r = 0; r < 4; ++r) {                                             \
      pa0[r] = __builtin_amdgcn_exp2f(stA[0][r]); LA += pa0[r];               \
      pa1[r] = __builtin_amdgcn_exp2f(stA[1][r]); LA += pa1[r];               \
      pa2[r] = __builtin_amdgcn_exp2f(stA[2][r]); LA += pa2[r];               \
      pa3[r] = __builtin_amdgcn_exp2f(stA[3][r]); LA += pa3[r];               \
    }                                                                         \
    {                                                                         \
      bf16x8 pf0 = __builtin_shufflevector(                                   \
          __builtin_convertvector(pa0, bf16x4),                               \
          __builtin_convertvector(pa1, bf16x4), 0, 1, 2, 3, 4, 5, 6, 7);      \
      bf16x8 pf1 = __builtin_shufflevector(                                   \
          __builtin_convertvector(pa2, bf16x4),                               \
          __builtin_convertvector(pa3, bf16x4), 0, 1, 2, 3, 4, 5, 6, 7);      \
      _Pragma("unroll")                                                       \
      for (int mt = 0; mt < 4; ++mt) {                                        \
        OA[mt] = MFMA16(vf0[mt], pf0, OA[mt]);                                \
        OA[mt] = MFMA16(vf1[mt], pf1, OA[mt]);                                \
      }                                                                       \
    }                                                                         \
    f32x4 pb0, pb1, pb2, pb3;                                                 \
    _Pragma("unroll")                                                         \
    for (int r = 0; r < 4; ++r) {                                             \
      pb0[r] = __builtin_amdgcn_exp2f(stB[0][r]); LB += pb0[r];               \
      pb1[r] = __builtin_amdgcn_exp2f(stB[1][r]); LB += pb1[r];               \
      pb2[r] = __builtin_amdgcn_exp2f(stB[2][r]); LB += pb2[r];               \
      pb3[r] = __builtin_amdgcn_exp2f(stB[3][r]); LB += pb3[r];               \
    }                                                                         \
    {                                                                         \
      bf16x8 pf0 = __builtin_shufflevector(                                   \
          __builtin_convertvector(pb0, bf16x4),                               \
          __builtin_convertvector(pb1, bf16x4), 0, 1, 2, 3, 4, 5, 6, 7);      \
      bf16x8 pf1 = __builtin_shufflevector(                                   \
          __builtin_convertvector(pb2, bf16x4),                               \
          __builtin_convertvector(pb3, bf16x4), 0, 1, 2, 3, 4, 5, 6, 7);      \
      _Pragma("unroll")                                                       \
      for (int mt = 0; mt < 4; ++mt) {                                        \
        OB[mt] = MFMA16(vf0[mt], pf0, OB[mt]);                                \
        OB[mt] = MFMA16(vf1[mt], pf1, OB[mt]);                                \
      }                                                                       \
    }                                                                         \
  } while (0)

  stage(0, 0);   // prologue

  for (int it = 0; it < SS / 64; ++it) {
    const int cur = it & 1;
    // Drain this wave's outstanding LDS-DMA (the prefetch of buf[cur]),
    // THEN barrier to publish cross-wave + protect the WAR on buf[cur^1].
    WAIT_VM0();
    __syncthreads();
    if (it + 1 < SS / 64) stage((it + 1) * 64, cur ^ 1);

    const u16* Kh = smem + cur * 4096;
    const u16* Vh = smem + 8192 + cur * 4096;

    // K and V frags read once (swizzled), register-held for all 4 q-sets
    bf16x8 kf0[4], kf1[4], vf0[4], vf1[4];
#pragma unroll
    for (int mt = 0; mt < 4; ++mt) {
      kf0[mt] = *(const bf16x8*)&Kh[(mt * 16 + cl) * 32 + sx];
      kf1[mt] = *(const bf16x8*)&Kh[(64 + mt * 16 + cl) * 32 + sx];
      vf0[mt] = *(const bf16x8*)&Vh[(mt * 16 + cl) * 32 + sx];
      vf1[mt] = *(const bf16x8*)&Vh[(64 + mt * 16 + cl) * 32 + sx];
    }

    PAIR(qf0a, qf0b, qf1a, qf1b, oacc0, oacc1, lsum0, lsum1);
    PAIR(qf2a, qf2b, qf3a, qf3b, oacc2, oacc3, lsum2, lsum3);
  }

  // cross-lane normalizer reduction (once)
  lsum0 += __shfl_xor(lsum0, 16); lsum0 += __shfl_xor(lsum0, 32);
  lsum1 += __shfl_xor(lsum1, 16); lsum1 += __shfl_xor(lsum1, 32);
  lsum2 += __shfl_xor(lsum2, 16); lsum2 += __shfl_xor(lsum2, 32);
  lsum3 += __shfl_xor(lsum3, 16); lsum3 += __shfl_xor(lsum3, 32);

  // epilogue: normalize, transpose O^T -> O via per-wave LDS slab, store fp32
  __syncthreads();
  float* Ol = (float*)smem;        // per-wave slab: 1088 floats (17408 B tot)
  const int q   = ln >> 2;
  const int seg = ln & 3;
  const float* src = Ol + w * 1088 + q * 68 + seg * 16;

#define EPI(OA, LS, SOFF) do {                                                \
    const float inv = 1.f / (LS);                                             \
    _Pragma("unroll")                                                         \
    for (int mt = 0; mt < 4; ++mt) {                                          \
      f32x4 vv = OA[mt];                                                      \
      _Pragma("unroll")                                                       \
      for (int r = 0; r < 4; ++r) vv[r] *= inv;                               \
      *(f32x4*)(Ol + w * 1088 + cl * 68 + mt * 16 + qd * 4) = vv;             \
    }                                                                         \
    {                                                                         \
      float* dst = Out + (size_t)(b * SS + q0 + (SOFF) + w * 16 + q) * DD     \
                       + h * DH + seg * 16;                                   \
      _Pragma("unroll")                                                       \
      for (int i = 0; i < 4; ++i)                                             \
        *(f32x4*)(dst + i * 4) = *(const f32x4*)(src + i * 4);                \
    }                                                                         \
  } while (0)

  EPI(oacc0, lsum0, 0);
  EPI(oacc1, lsum1, 64);
  EPI(oacc2, lsum2, 128);
  EPI(oacc3, lsum3, 192);

#undef EPI
#undef PAIR
}

// ---------------------------------------------------------------------------
extern "C" void kernel_launch(void* const* d_in, const int* in_sizes, int n_in,
                              void* d_out, int out_size, void* d_ws, size_t ws_size,
                              hipStream_t stream)
{
  const float* x  = (const float*)d_in[0];
  const float* wq = (const float*)d_in[1];
  const float* wk = (const float*)d_in[2];
  const float* wv = (const float*)d_in[3];
  float* out = (float*)d_out;

  // ws (bf16): xs 16MB | wt 6MB | qkv 48MB | vtg 16MB = 86MB
  const size_t need = ((size_t)MM * DD + 3 * (size_t)DD * DD +
                       3 * (size_t)MM * DD + (size_t)MM * DD) * sizeof(u16);
  if (ws_size < need) {
    fill_sig<<<1024, 256, 0, stream>>>(out, out_size);
    return;
  }

  u16* xs  = (u16*)d_ws;
  u16* wt  = xs + (size_t)MM * DD;
  u16* qkv = wt + (size_t)3 * DD * DD;
  u16* vtg = qkv + (size_t)3 * MM * DD;

  // 4 launches: convert_x (2048 blocks — the R8 256-block merge was the
  // regression), convert_w, qkv (+fused V-transpose), attn.
  convert_x<<<2048, 256, 0, stream>>>(x, xs);
  convert_w<<<dim3(16, 16, 3), 256, 0, stream>>>(wq, wk, wv, wt);
  qkv_gemm<<<dim3(64, 8, 3), 256, 0, stream>>>(xs, wt, qkv, vtg);
  attn_kernel<<<dim3(HH * BB, SS / 256, 1), 256, 0, stream>>>(qkv, vtg, out);
}